// Round 5
// baseline (255.460 us; speedup 1.0000x reference)
//
#include <hip/hip_runtime.h>
#include <hip/hip_bf16.h>
#include <stdint.h>

// Problem constants (GQA: D=1024, 16 heads, 4 groups, hd=64)
#define D_MODEL 1024
#define T_LEN   2048
#define BATCH   2
#define N_HEADS 16
#define KV_DIM  256
#define QKV_N   1536              // 1024 + 256 + 256 fused projection width
#define M_ROWS  (BATCH * T_LEN)   // 4096

typedef unsigned short u16;
typedef __bf16 bf16x8 __attribute__((ext_vector_type(8)));
typedef __bf16 bf16x2 __attribute__((ext_vector_type(2)));
typedef float  f32x4  __attribute__((ext_vector_type(4)));

__device__ __forceinline__ u16 f2b(float f) {
    uint32_t u = __builtin_bit_cast(uint32_t, f);
    u += 0x7FFFu + ((u >> 16) & 1u);   // round-to-nearest-even
    return (u16)(u >> 16);
}

// pack two f32 -> two bf16 in one u32 (lo = a, hi = b)
__device__ __forceinline__ uint32_t pk_bf16(float a, float b) {
#if __has_builtin(__builtin_amdgcn_cvt_pk_bf16_f32)
    bf16x2 v = __builtin_amdgcn_cvt_pk_bf16_f32(a, b);
    return __builtin_bit_cast(uint32_t, v);
#else
    return (uint32_t)f2b(a) | ((uint32_t)f2b(b) << 16);
#endif
}

// async global->LDS, 16B per lane; LDS dest = wave-uniform base + lane*16
__device__ __forceinline__ void gl_lds16(const void* g, void* l) {
    __builtin_amdgcn_global_load_lds(g, l, 16, 0, 0);
}

// ---------------------------------------------------------------------------
// fp32 -> bf16 elementwise convert (row-major preserved). 8 elems/thread.
// ---------------------------------------------------------------------------
__global__ __launch_bounds__(256) void cvt_f32_bf16(
    const float* __restrict__ in, u16* __restrict__ out, int n)
{
    int i = (blockIdx.x * 256 + threadIdx.x) * 8;
    if (i >= n) return;
    float4 a = *(const float4*)&in[i];
    float4 c = *(const float4*)&in[i + 4];
    u16 r[8] = { f2b(a.x), f2b(a.y), f2b(a.z), f2b(a.w),
                 f2b(c.x), f2b(c.y), f2b(c.z), f2b(c.w) };
    *(uint4*)&out[i] = *(const uint4*)r;
}

// ---------------------------------------------------------------------------
// All-weights transpose + convert, one launch.
// grid.x tiles: [0,32) Wq, [32,40) Wk, [40,48) Wv, [48,80) Wo. K=1024 always.
// ---------------------------------------------------------------------------
__global__ __launch_bounds__(256) void transpose_all(
    const float* __restrict__ Wq, const float* __restrict__ Wk,
    const float* __restrict__ Wv, const float* __restrict__ Wo,
    u16* __restrict__ WcatT, u16* __restrict__ WoT)
{
    __shared__ u16 tile[32][33];
    int bx = blockIdx.x;
    const float* src; u16* dst; int N, n0;
    if (bx < 32)       { src = Wq; dst = WcatT;                   N = 1024; n0 = bx * 32; }
    else if (bx < 40)  { src = Wk; dst = WcatT + 1024 * 1024;     N = 256;  n0 = (bx - 32) * 32; }
    else if (bx < 48)  { src = Wv; dst = WcatT + 1280 * 1024;     N = 256;  n0 = (bx - 40) * 32; }
    else               { src = Wo; dst = WoT;                     N = 1024; n0 = (bx - 48) * 32; }
    int k0 = blockIdx.y * 32;
    int tid = threadIdx.x;
    for (int i = 0; i < 4; ++i) {
        int idx = tid + i * 256;
        int r = idx >> 5, c = idx & 31;
        tile[r][c] = f2b(src[(size_t)(k0 + r) * N + (n0 + c)]);
    }
    __syncthreads();
    for (int i = 0; i < 4; ++i) {
        int idx = tid + i * 256;
        int r = idx >> 5, c = idx & 31;   // r: n-local, c: k-local
        dst[(size_t)(n0 + r) * 1024 + (k0 + c)] = tile[c][r];
    }
}

// ---------------------------------------------------------------------------
// Fused QKV GEMM (m97-style staging): [M x 1536] = x * WcatT^T + bias.
// Q written PRE-SCALED by 1/sqrt(64)*log2(e); K row-major; V transposed into
// Vt_glob[256 x M]. LDS unpadded [128][64], staged via global_load_lds x16B.
// ---------------------------------------------------------------------------
__global__ __launch_bounds__(256) void gemm_qkv(
    const u16* __restrict__ A, const u16* __restrict__ BT,
    const float* __restrict__ bq, const float* __restrict__ bk,
    const float* __restrict__ bv, u16* __restrict__ C,
    u16* __restrict__ Vt_glob)
{
    constexpr int K = 1024;
    constexpr float SCALE = 0.125f * 1.44269504088896f;
    __shared__ __align__(16) u16 As[128 * 64];
    __shared__ __align__(16) u16 Bs[128 * 64];

    int tid  = threadIdx.x;
    int lane = tid & 63, w = tid >> 6;
    int wm = w & 1, wn = w >> 1;
    int quad = lane >> 4, l15 = lane & 15;
    int m0 = blockIdx.y * 128, n0 = blockIdx.x * 128;
    int lr = lane >> 3, lc = (lane & 7) * 8;   // 8 rows x 64 cols per 1KB chunk

    f32x4 acc[4][4] = {};

    for (int k0 = 0; k0 < K; k0 += 64) {
        for (int t = 0; t < 4; ++t) {
            int rb = w * 32 + t * 8;
            gl_lds16(&A[(size_t)(m0 + rb + lr) * K + k0 + lc], &As[rb * 64]);
            gl_lds16(&BT[(size_t)(n0 + rb + lr) * K + k0 + lc], &Bs[rb * 64]);
        }
        __syncthreads();
        for (int kk = 0; kk < 64; kk += 32) {
            bf16x8 a[4], b[4];
            for (int i = 0; i < 4; ++i)
                a[i] = *(const bf16x8*)&As[(wm * 64 + i * 16 + l15) * 64 + kk + quad * 8];
            for (int j = 0; j < 4; ++j)
                b[j] = *(const bf16x8*)&Bs[(wn * 64 + j * 16 + l15) * 64 + kk + quad * 8];
            for (int i = 0; i < 4; ++i)
                for (int j = 0; j < 4; ++j)
                    acc[i][j] = __builtin_amdgcn_mfma_f32_16x16x32_bf16(
                        a[i], b[j], acc[i][j], 0, 0, 0);
        }
        __syncthreads();
    }

    for (int j = 0; j < 4; ++j) {
        int col = n0 + wn * 64 + j * 16 + l15;
        float bj = (col < 1024) ? bq[col] : (col < 1280) ? bk[col - 1024] : bv[col - 1280];
        for (int i = 0; i < 4; ++i) {
            int rowb = m0 + wm * 64 + i * 16 + quad * 4;
            if (col < 1024) {
                for (int r = 0; r < 4; ++r)
                    C[(size_t)(rowb + r) * QKV_N + col] = f2b((acc[i][j][r] + bj) * SCALE);
            } else if (col < 1280) {
                for (int r = 0; r < 4; ++r)
                    C[(size_t)(rowb + r) * QKV_N + col] = f2b(acc[i][j][r] + bj);
            } else {
                u16 tmp[4];
                for (int r = 0; r < 4; ++r) tmp[r] = f2b(acc[i][j][r] + bj);
                *(uint64_t*)&Vt_glob[(size_t)(col - 1280) * M_ROWS + rowb] =
                    *(const uint64_t*)tmp;
            }
        }
    }
}

// ---------------------------------------------------------------------------
// Out-proj GEMM (m97-style staging): out[M x 1024](fp32) = AO * WoT^T + bo.
// ---------------------------------------------------------------------------
__global__ __launch_bounds__(256) void gemm_out(
    const u16* __restrict__ A, const u16* __restrict__ BT,
    const float* __restrict__ bias, float* __restrict__ C)
{
    constexpr int K = 1024, N = 1024;
    __shared__ __align__(16) u16 As[128 * 64];
    __shared__ __align__(16) u16 Bs[128 * 64];

    int tid  = threadIdx.x;
    int lane = tid & 63, w = tid >> 6;
    int wm = w & 1, wn = w >> 1;
    int quad = lane >> 4, l15 = lane & 15;
    int m0 = blockIdx.y * 128, n0 = blockIdx.x * 128;
    int lr = lane >> 3, lc = (lane & 7) * 8;

    f32x4 acc[4][4] = {};

    for (int k0 = 0; k0 < K; k0 += 64) {
        for (int t = 0; t < 4; ++t) {
            int rb = w * 32 + t * 8;
            gl_lds16(&A[(size_t)(m0 + rb + lr) * K + k0 + lc], &As[rb * 64]);
            gl_lds16(&BT[(size_t)(n0 + rb + lr) * K + k0 + lc], &Bs[rb * 64]);
        }
        __syncthreads();
        for (int kk = 0; kk < 64; kk += 32) {
            bf16x8 a[4], b[4];
            for (int i = 0; i < 4; ++i)
                a[i] = *(const bf16x8*)&As[(wm * 64 + i * 16 + l15) * 64 + kk + quad * 8];
            for (int j = 0; j < 4; ++j)
                b[j] = *(const bf16x8*)&Bs[(wn * 64 + j * 16 + l15) * 64 + kk + quad * 8];
            for (int i = 0; i < 4; ++i)
                for (int j = 0; j < 4; ++j)
                    acc[i][j] = __builtin_amdgcn_mfma_f32_16x16x32_bf16(
                        a[i], b[j], acc[i][j], 0, 0, 0);
        }
        __syncthreads();
    }

    for (int j = 0; j < 4; ++j) {
        int col = n0 + wn * 64 + j * 16 + l15;
        float bj = bias[col];
        for (int i = 0; i < 4; ++i) {
            int rowb = m0 + wm * 64 + i * 16 + quad * 4;
            for (int r = 0; r < 4; ++r)
                C[(size_t)(rowb + r) * N + col] = acc[i][j][r] + bj;
        }
    }
}

// ---------------------------------------------------------------------------
// Flash attention (causal, GQA). One block = (b, head, 64-row q-tile).
// Q arrives pre-scaled (log2 domain). Computes S^T = K*Q^T so each lane holds
// 4 consecutive keys per q-row -> packed bf16 P stores (4x ds_write_b64).
// Fixed-max softmax: interior iters are exp2+add only; mask on diagonal tile.
// l = scalar per lane, reduced once in epilogue. V pre-transposed in global.
// ---------------------------------------------------------------------------
__global__ __launch_bounds__(256) void attn_kernel(
    const u16* __restrict__ QKV,     // [B*T, 1536] bf16 (Qscaled | K | -)
    const u16* __restrict__ Vt_glob, // [256, B*T]  bf16 (V transposed)
    u16* __restrict__ AO)            // [B*T, 1024] bf16
{
    constexpr int LDT = 72;
    __shared__ __align__(16) u16 Qs[64 * LDT];
    __shared__ __align__(16) u16 Ks[64 * LDT];
    __shared__ __align__(16) u16 Vt[64 * LDT];
    __shared__ __align__(16) u16 Ps[64 * LDT];

    int tid  = threadIdx.x;
    int lane = tid & 63, w = tid >> 6;
    int quad = lane >> 4, l15 = lane & 15;
    int head = blockIdx.y, b = blockIdx.z;
    int qt = (blockIdx.x + head + 16 * b) & 31;   // work-balance swizzle
    int g  = head >> 2;                           // 4 heads per KV group
    int q0 = qt * 64;

    const u16* Qp = QKV + (size_t)b * T_LEN * QKV_N + head * 64;
    const u16* Kp = QKV + (size_t)b * T_LEN * QKV_N + 1024 + g * 64;
    const u16* Vp = Vt_glob + (size_t)g * 64 * M_ROWS + b * T_LEN;
    u16*       Op = AO  + (size_t)b * T_LEN * D_MODEL + head * 64;

    // stage Q tile [64 x 64]
    for (int i = 0; i < 2; ++i) {
        int id = tid + 256 * i;
        int r = id >> 3, c = (id & 7) << 3;
        *(uint4*)&Qs[r * LDT + c] =
            *(const uint4*)&Qp[(size_t)(q0 + r) * QKV_N + c];
    }

    f32x4 o[4] = {};
    float lsum = 0.f;

    // prefetch k-tile 0 into registers
    uint4 Kreg[2], Vreg[2];
    for (int i = 0; i < 2; ++i) {
        int id = tid + 256 * i;
        int r = id >> 3, c = (id & 7) << 3;
        Kreg[i] = *(const uint4*)&Kp[(size_t)r * QKV_N + c];
        Vreg[i] = *(const uint4*)&Vp[(size_t)r * M_ROWS + c];   // r = d row
    }

    for (int kt = 0; kt <= qt; ++kt) {
        bool diag = (kt == qt);
        __syncthreads();   // prior-iter reads of Ks/Vt done; (kt=0: Qs visible)
        for (int i = 0; i < 2; ++i) {
            int id = tid + 256 * i;
            int r = id >> 3, c = (id & 7) << 3;
            *(uint4*)&Ks[r * LDT + c] = Kreg[i];
            *(uint4*)&Vt[r * LDT + c] = Vreg[i];
        }
        __syncthreads();
        if (!diag) {
            int k0n = (kt + 1) * 64;
            for (int i = 0; i < 2; ++i) {
                int id = tid + 256 * i;
                int r = id >> 3, c = (id & 7) << 3;
                Kreg[i] = *(const uint4*)&Kp[(size_t)(k0n + r) * QKV_N + c];
                Vreg[i] = *(const uint4*)&Vp[(size_t)r * M_ROWS + k0n + c];
            }
        }

        // S^T = K * Q^T  (A=K: m=key, B=Q: n=qrow). Wave w: qrows w*16..+15.
        // D layout: row(quad*4+reg)=key, col(l15)=qrow.
        f32x4 s[4] = {};
        for (int kk = 0; kk < 2; ++kk) {
            bf16x8 bQ = *(const bf16x8*)&Qs[(w * 16 + l15) * LDT + kk * 32 + quad * 8];
            for (int nt = 0; nt < 4; ++nt) {
                bf16x8 aK = *(const bf16x8*)&Ks[(nt * 16 + l15) * LDT + kk * 32 + quad * 8];
                s[nt] = __builtin_amdgcn_mfma_f32_16x16x32_bf16(aK, bQ, s[nt], 0, 0, 0);
            }
        }

        // exp2 (Q pre-scaled, log2 domain) + l partial + packed P store.
        // Lane (quad,l15): qrow = w*16+l15, keys = nt*16 + quad*4 + {0..3}.
        int lim = w * 16 + l15;   // causal limit (local), diagonal tile only
        for (int nt = 0; nt < 4; ++nt) {
            float p0, p1, p2, p3;
            if (diag) {
                int kl = nt * 16 + quad * 4;
                p0 = (kl + 0 <= lim) ? exp2f(s[nt][0]) : 0.f;
                p1 = (kl + 1 <= lim) ? exp2f(s[nt][1]) : 0.f;
                p2 = (kl + 2 <= lim) ? exp2f(s[nt][2]) : 0.f;
                p3 = (kl + 3 <= lim) ? exp2f(s[nt][3]) : 0.f;
            } else {
                p0 = exp2f(s[nt][0]);
                p1 = exp2f(s[nt][1]);
                p2 = exp2f(s[nt][2]);
                p3 = exp2f(s[nt][3]);
            }
            lsum += (p0 + p1) + (p2 + p3);
            uint2 pr;
            pr.x = pk_bf16(p0, p1);
            pr.y = pk_bf16(p2, p3);
            *(uint2*)&Ps[(w * 16 + l15) * LDT + nt * 16 + quad * 4] = pr;
        }

        // O += P V  (A=P[q][key] rows w*16+l15 — wave-private; B=Vt[d][key])
        for (int kk = 0; kk < 2; ++kk) {
            bf16x8 aP = *(const bf16x8*)&Ps[(w * 16 + l15) * LDT + kk * 32 + quad * 8];
            for (int dt = 0; dt < 4; ++dt) {
                bf16x8 bV = *(const bf16x8*)&Vt[(dt * 16 + l15) * LDT + kk * 32 + quad * 8];
                o[dt] = __builtin_amdgcn_mfma_f32_16x16x32_bf16(aP, bV, o[dt], 0, 0, 0);
            }
        }
    }

    // epilogue: reduce l across quads (lanes sharing l15), broadcast, store.
    lsum += __shfl_xor(lsum, 16, 64);
    lsum += __shfl_xor(lsum, 32, 64);
    float linv = 1.0f / lsum;      // for qrow w*16 + l15
    float li[4];
    for (int r = 0; r < 4; ++r)
        li[r] = __shfl(linv, quad * 4 + r, 64);   // qrow w*16 + quad*4 + r
    for (int dt = 0; dt < 4; ++dt)
        for (int r = 0; r < 4; ++r)
            Op[(size_t)(q0 + w * 16 + quad * 4 + r) * D_MODEL + dt * 16 + l15] =
                f2b(o[dt][r] * li[r]);
}

// ---------------------------------------------------------------------------
extern "C" void kernel_launch(void* const* d_in, const int* in_sizes, int n_in,
                              void* d_out, int out_size, void* d_ws, size_t ws_size,
                              hipStream_t stream) {
    const float* x  = (const float*)d_in[0];
    const float* Wq = (const float*)d_in[1];
    const float* bq = (const float*)d_in[2];
    const float* Wk = (const float*)d_in[3];
    const float* bk = (const float*)d_in[4];
    const float* Wv = (const float*)d_in[5];
    const float* bv = (const float*)d_in[6];
    const float* Wo = (const float*)d_in[7];
    const float* bo = (const float*)d_in[8];
    float* out = (float*)d_out;

    u16* ws    = (u16*)d_ws;
    u16* xb    = ws;  ws += (size_t)M_ROWS * 1024;   // x bf16; reused as AO
    u16* WcatT = ws;  ws += (size_t)QKV_N * 1024;
    u16* WoT   = ws;  ws += 1024 * 1024;
    u16* QKV   = ws;  ws += (size_t)M_ROWS * QKV_N;
    u16* Vt_g  = ws;  ws += (size_t)KV_DIM * M_ROWS;
    u16* AO    = xb;                                  // alias: xb dead after gemm_qkv
    // total ws use: ~29 MB

    int nx = M_ROWS * 1024;
    cvt_f32_bf16<<<nx / (256 * 8), 256, 0, stream>>>(x, xb, nx);
    transpose_all<<<dim3(80, 32), 256, 0, stream>>>(Wq, Wk, Wv, Wo, WcatT, WoT);
    gemm_qkv<<<dim3(QKV_N / 128, M_ROWS / 128), 256, 0, stream>>>(
        xb, WcatT, bq, bk, bv, QKV, Vt_g);
    attn_kernel<<<dim3(T_LEN / 64, N_HEADS, BATCH), 256, 0, stream>>>(QKV, Vt_g, AO);
    gemm_out<<<dim3(1024 / 128, M_ROWS / 128), 256, 0, stream>>>(AO, WoT, bo, out);
}

// Round 6
// 210.483 us; speedup vs baseline: 1.2137x; 1.2137x over previous
//
#include <hip/hip_runtime.h>
#include <hip/hip_bf16.h>
#include <stdint.h>

// Problem constants (GQA: D=1024, 16 heads, 4 groups, hd=64)
#define D_MODEL 1024
#define T_LEN   2048
#define BATCH   2
#define N_HEADS 16
#define KV_DIM  256
#define QKV_N   1536              // 1024 + 256 + 256 fused projection width
#define M_ROWS  (BATCH * T_LEN)   // 4096

typedef unsigned short u16;
typedef __bf16 bf16x8 __attribute__((ext_vector_type(8)));
typedef __bf16 bf16x2 __attribute__((ext_vector_type(2)));
typedef float  f32x4  __attribute__((ext_vector_type(4)));

__device__ __forceinline__ u16 f2b(float f) {
    uint32_t u = __builtin_bit_cast(uint32_t, f);
    u += 0x7FFFu + ((u >> 16) & 1u);   // round-to-nearest-even
    return (u16)(u >> 16);
}

// pack two f32 -> two bf16 in one u32 (lo = a, hi = b)
__device__ __forceinline__ uint32_t pk_bf16(float a, float b) {
#if __has_builtin(__builtin_amdgcn_cvt_pk_bf16_f32)
    bf16x2 v = __builtin_amdgcn_cvt_pk_bf16_f32(a, b);
    return __builtin_bit_cast(uint32_t, v);
#else
    return (uint32_t)f2b(a) | ((uint32_t)f2b(b) << 16);
#endif
}

// async global->LDS, 16B per lane; LDS dest = wave-uniform base + lane*16
__device__ __forceinline__ void gl_lds16(const void* g, void* l) {
    __builtin_amdgcn_global_load_lds(g, l, 16, 0, 0);
}

// ---------------------------------------------------------------------------
// fp32 -> bf16 elementwise convert. 8 elems/thread.
// ---------------------------------------------------------------------------
__global__ __launch_bounds__(256) void cvt_f32_bf16(
    const float* __restrict__ in, u16* __restrict__ out, int n)
{
    int i = (blockIdx.x * 256 + threadIdx.x) * 8;
    if (i >= n) return;
    float4 a = *(const float4*)&in[i];
    float4 c = *(const float4*)&in[i + 4];
    u16 r[8] = { f2b(a.x), f2b(a.y), f2b(a.z), f2b(a.w),
                 f2b(c.x), f2b(c.y), f2b(c.z), f2b(c.w) };
    *(uint4*)&out[i] = *(const uint4*)r;
}

// ---------------------------------------------------------------------------
// All-weights transpose + convert, one launch.
// grid.x tiles: [0,32) Wq, [32,40) Wk, [40,48) Wv, [48,80) Wo. K=1024 always.
// ---------------------------------------------------------------------------
__global__ __launch_bounds__(256) void transpose_all(
    const float* __restrict__ Wq, const float* __restrict__ Wk,
    const float* __restrict__ Wv, const float* __restrict__ Wo,
    u16* __restrict__ WcatT, u16* __restrict__ WoT)
{
    __shared__ u16 tile[32][33];
    int bx = blockIdx.x;
    const float* src; u16* dst; int N, n0;
    if (bx < 32)       { src = Wq; dst = WcatT;                   N = 1024; n0 = bx * 32; }
    else if (bx < 40)  { src = Wk; dst = WcatT + 1024 * 1024;     N = 256;  n0 = (bx - 32) * 32; }
    else if (bx < 48)  { src = Wv; dst = WcatT + 1280 * 1024;     N = 256;  n0 = (bx - 40) * 32; }
    else               { src = Wo; dst = WoT;                     N = 1024; n0 = (bx - 48) * 32; }
    int k0 = blockIdx.y * 32;
    int tid = threadIdx.x;
    for (int i = 0; i < 4; ++i) {
        int idx = tid + i * 256;
        int r = idx >> 5, c = idx & 31;
        tile[r][c] = f2b(src[(size_t)(k0 + r) * N + (n0 + c)]);
    }
    __syncthreads();
    for (int i = 0; i < 4; ++i) {
        int idx = tid + i * 256;
        int r = idx >> 5, c = idx & 31;   // r: n-local, c: k-local
        dst[(size_t)(n0 + r) * 1024 + (k0 + c)] = tile[c][r];
    }
}

// ---------------------------------------------------------------------------
// Fused QKV GEMM, 64x128 tile (M x N), 256 threads, wave w -> cols w*32..+31.
// Q written PRE-SCALED by 1/sqrt(64)*log2(e); K row-major; V transposed into
// Vt_glob[256 x M]. LDS unpadded, staged via global_load_lds 16B.
// Grid 768 blocks (~3/CU) for wave-level overlap.
// ---------------------------------------------------------------------------
__global__ __launch_bounds__(256) void gemm_qkv(
    const u16* __restrict__ A, const u16* __restrict__ BT,
    const float* __restrict__ bq, const float* __restrict__ bk,
    const float* __restrict__ bv, u16* __restrict__ C,
    u16* __restrict__ Vt_glob)
{
    constexpr int K = 1024;
    constexpr float SCALE = 0.125f * 1.44269504088896f;
    __shared__ __align__(16) u16 As[64 * 64];
    __shared__ __align__(16) u16 Bs[128 * 64];

    int tid  = threadIdx.x;
    int lane = tid & 63, w = tid >> 6;
    int quad = lane >> 4, l15 = lane & 15;
    int m0 = blockIdx.y * 64, n0 = blockIdx.x * 128;
    int lr = lane >> 3, lc = (lane & 7) * 8;

    f32x4 acc[4][2] = {};

    for (int k0 = 0; k0 < K; k0 += 64) {
        for (int t = 0; t < 2; ++t) {
            int rb = t * 32 + w * 8;
            gl_lds16(&A[(size_t)(m0 + rb + lr) * K + k0 + lc], &As[rb * 64]);
        }
        for (int t = 0; t < 4; ++t) {
            int rb = t * 32 + w * 8;
            gl_lds16(&BT[(size_t)(n0 + rb + lr) * K + k0 + lc], &Bs[rb * 64]);
        }
        __syncthreads();
        for (int kk = 0; kk < 64; kk += 32) {
            bf16x8 a[4], b[2];
            for (int i = 0; i < 4; ++i)
                a[i] = *(const bf16x8*)&As[(i * 16 + l15) * 64 + kk + quad * 8];
            for (int j = 0; j < 2; ++j)
                b[j] = *(const bf16x8*)&Bs[(w * 32 + j * 16 + l15) * 64 + kk + quad * 8];
            for (int i = 0; i < 4; ++i)
                for (int j = 0; j < 2; ++j)
                    acc[i][j] = __builtin_amdgcn_mfma_f32_16x16x32_bf16(
                        a[i], b[j], acc[i][j], 0, 0, 0);
        }
        __syncthreads();
    }

    for (int j = 0; j < 2; ++j) {
        int col = n0 + w * 32 + j * 16 + l15;
        float bj = (col < 1024) ? bq[col] : (col < 1280) ? bk[col - 1024] : bv[col - 1280];
        for (int i = 0; i < 4; ++i) {
            int rowb = m0 + i * 16 + quad * 4;
            if (col < 1024) {
                for (int r = 0; r < 4; ++r)
                    C[(size_t)(rowb + r) * QKV_N + col] = f2b((acc[i][j][r] + bj) * SCALE);
            } else if (col < 1280) {
                for (int r = 0; r < 4; ++r)
                    C[(size_t)(rowb + r) * QKV_N + col] = f2b(acc[i][j][r] + bj);
            } else {
                u16 tmp[4];
                for (int r = 0; r < 4; ++r) tmp[r] = f2b(acc[i][j][r] + bj);
                *(uint64_t*)&Vt_glob[(size_t)(col - 1280) * M_ROWS + rowb] =
                    *(const uint64_t*)tmp;
            }
        }
    }
}

// ---------------------------------------------------------------------------
// Out-proj GEMM, 64x128 tile: out[M x 1024](fp32) = AO * WoT^T + bo.
// Grid 512 blocks (2/CU).
// ---------------------------------------------------------------------------
__global__ __launch_bounds__(256) void gemm_out(
    const u16* __restrict__ A, const u16* __restrict__ BT,
    const float* __restrict__ bias, float* __restrict__ C)
{
    constexpr int K = 1024, N = 1024;
    __shared__ __align__(16) u16 As[64 * 64];
    __shared__ __align__(16) u16 Bs[128 * 64];

    int tid  = threadIdx.x;
    int lane = tid & 63, w = tid >> 6;
    int quad = lane >> 4, l15 = lane & 15;
    int m0 = blockIdx.y * 64, n0 = blockIdx.x * 128;
    int lr = lane >> 3, lc = (lane & 7) * 8;

    f32x4 acc[4][2] = {};

    for (int k0 = 0; k0 < K; k0 += 64) {
        for (int t = 0; t < 2; ++t) {
            int rb = t * 32 + w * 8;
            gl_lds16(&A[(size_t)(m0 + rb + lr) * K + k0 + lc], &As[rb * 64]);
        }
        for (int t = 0; t < 4; ++t) {
            int rb = t * 32 + w * 8;
            gl_lds16(&BT[(size_t)(n0 + rb + lr) * K + k0 + lc], &Bs[rb * 64]);
        }
        __syncthreads();
        for (int kk = 0; kk < 64; kk += 32) {
            bf16x8 a[4], b[2];
            for (int i = 0; i < 4; ++i)
                a[i] = *(const bf16x8*)&As[(i * 16 + l15) * 64 + kk + quad * 8];
            for (int j = 0; j < 2; ++j)
                b[j] = *(const bf16x8*)&Bs[(w * 32 + j * 16 + l15) * 64 + kk + quad * 8];
            for (int i = 0; i < 4; ++i)
                for (int j = 0; j < 2; ++j)
                    acc[i][j] = __builtin_amdgcn_mfma_f32_16x16x32_bf16(
                        a[i], b[j], acc[i][j], 0, 0, 0);
        }
        __syncthreads();
    }

    for (int j = 0; j < 2; ++j) {
        int col = n0 + w * 32 + j * 16 + l15;
        float bj = bias[col];
        for (int i = 0; i < 4; ++i) {
            int rowb = m0 + i * 16 + quad * 4;
            for (int r = 0; r < 4; ++r)
                C[(size_t)(rowb + r) * N + col] = acc[i][j][r] + bj;
        }
    }
}

// ---------------------------------------------------------------------------
// Flash attention v2 (causal, GQA-shared). One block = (b, group, 32-row
// q-strip); 4 waves = the group's 4 heads. K/V staged to LDS once per k-tile
// for ALL 4 heads. Q fragments loop-invariant in registers. Fixed-max softmax
// (Q pre-scaled to log2 domain), mask only on last k-tile, l reduced once.
// Grid 512 flat: ids<256 -> strips 0..31, ids>=256 -> strips 63..32 so
// co-resident pairs (id, id+256) total exactly 33 k-iters (balanced); blocks
// sharing (g,b) share id%8 -> same XCD -> K/V L2 locality.
// ---------------------------------------------------------------------------
__global__ __launch_bounds__(256) void attn_kernel(
    const u16* __restrict__ QKV,     // [B*T, 1536] bf16 (Qscaled | K | -)
    const u16* __restrict__ Vt_glob, // [256, B*T]  bf16 (V transposed)
    u16* __restrict__ AO)            // [B*T, 1024] bf16
{
    constexpr int LDT = 72;
    __shared__ __align__(16) u16 Ks[64 * LDT];
    __shared__ __align__(16) u16 Vt[64 * LDT];
    __shared__ __align__(16) u16 Ps[4 * 32 * LDT];

    int tid  = threadIdx.x;
    int lane = tid & 63, w = tid >> 6;
    int quad = lane >> 4, l15 = lane & 15;

    int gid  = blockIdx.x;
    int half = gid >> 8, rid = gid & 255;
    int j = half ? (63 - (rid >> 3)) : (rid >> 3);   // q-strip (32 rows)
    int g = (rid >> 1) & 3;
    int b = rid & 1;
    int head = g * 4 + w;                            // wave = head
    int q0 = j * 32;
    int iters = (j >> 1) + 1;                        // k-tiles of 64 keys

    const u16* Qp = QKV + ((size_t)b * T_LEN + q0) * QKV_N + head * 64;
    const u16* Kp = QKV + (size_t)b * T_LEN * QKV_N + 1024 + g * 64;
    const u16* Vp = Vt_glob + (size_t)g * 64 * M_ROWS + b * T_LEN;
    u16*       Op = AO + ((size_t)b * T_LEN + q0) * D_MODEL + head * 64;
    u16* Pw = Ps + w * 32 * LDT;                     // wave-private P tile

    // Q fragments (loop-invariant): B-frag Q[n=qrow][k], 2 ntq x 2 kk
    bf16x8 Qfrag[2][2];
    for (int ntq = 0; ntq < 2; ++ntq)
        for (int kk = 0; kk < 2; ++kk)
            Qfrag[ntq][kk] = *(const bf16x8*)
                &Qp[(size_t)(ntq * 16 + l15) * QKV_N + kk * 32 + quad * 8];

    f32x4 o[2][4] = {};
    float lsum[2] = {0.f, 0.f};

    // prefetch k-tile 0
    uint4 Kreg[2], Vreg[2];
    {
        int id0 = tid, id1 = tid + 256;
        Kreg[0] = *(const uint4*)&Kp[(size_t)(id0 >> 3) * QKV_N + ((id0 & 7) << 3)];
        Kreg[1] = *(const uint4*)&Kp[(size_t)(id1 >> 3) * QKV_N + ((id1 & 7) << 3)];
        Vreg[0] = *(const uint4*)&Vp[(size_t)(id0 >> 3) * M_ROWS + ((id0 & 7) << 3)];
        Vreg[1] = *(const uint4*)&Vp[(size_t)(id1 >> 3) * M_ROWS + ((id1 & 7) << 3)];
    }

    for (int kt = 0; kt < iters; ++kt) {
        bool last = (kt == iters - 1);
        __syncthreads();   // prior-iter frag reads of Ks/Vt complete
        for (int i = 0; i < 2; ++i) {
            int id = tid + 256 * i;
            int r = id >> 3, c = (id & 7) << 3;
            *(uint4*)&Ks[r * LDT + c] = Kreg[i];
            *(uint4*)&Vt[r * LDT + c] = Vreg[i];
        }
        __syncthreads();
        if (!last) {
            int k0n = (kt + 1) * 64;
            for (int i = 0; i < 2; ++i) {
                int id = tid + 256 * i;
                int r = id >> 3, c = (id & 7) << 3;
                Kreg[i] = *(const uint4*)&Kp[(size_t)(k0n + r) * QKV_N + c];
                Vreg[i] = *(const uint4*)&Vp[(size_t)r * M_ROWS + k0n + c];
            }
        }

        for (int ntq = 0; ntq < 2; ++ntq) {
            // S^T = K * Q^T : A=K (m=key tile ntk), B=Q (n=qrow).
            // D: row(quad*4+reg)=key, col(l15)=qrow (relative to ntq*16).
            f32x4 s[4] = {};
            for (int kk = 0; kk < 2; ++kk) {
                bf16x8 bQ = Qfrag[ntq][kk];
                for (int ntk = 0; ntk < 4; ++ntk) {
                    bf16x8 aK = *(const bf16x8*)
                        &Ks[(ntk * 16 + l15) * LDT + kk * 32 + quad * 8];
                    s[ntk] = __builtin_amdgcn_mfma_f32_16x16x32_bf16(
                        aK, bQ, s[ntk], 0, 0, 0);
                }
            }

            // exp2 (log2 domain) + causal mask (last tile) + l + packed P
            int qrow = q0 + ntq * 16 + l15;    // global q row
            float lacc = 0.f;
            for (int ntk = 0; ntk < 4; ++ntk) {
                float p0, p1, p2, p3;
                if (last) {
                    int key = kt * 64 + ntk * 16 + quad * 4;
                    p0 = (key + 0 <= qrow) ? exp2f(s[ntk][0]) : 0.f;
                    p1 = (key + 1 <= qrow) ? exp2f(s[ntk][1]) : 0.f;
                    p2 = (key + 2 <= qrow) ? exp2f(s[ntk][2]) : 0.f;
                    p3 = (key + 3 <= qrow) ? exp2f(s[ntk][3]) : 0.f;
                } else {
                    p0 = exp2f(s[ntk][0]);
                    p1 = exp2f(s[ntk][1]);
                    p2 = exp2f(s[ntk][2]);
                    p3 = exp2f(s[ntk][3]);
                }
                lacc += (p0 + p1) + (p2 + p3);
                uint2 pr;
                pr.x = pk_bf16(p0, p1);
                pr.y = pk_bf16(p2, p3);
                *(uint2*)&Pw[(ntq * 16 + l15) * LDT + ntk * 16 + quad * 4] = pr;
            }
            lsum[ntq] += lacc;

            // O += P V  (A=P rows ntq*16.. — wave-private, DS in-order;
            //            B=Vt[d][key])
            for (int kk = 0; kk < 2; ++kk) {
                bf16x8 aP = *(const bf16x8*)
                    &Pw[(ntq * 16 + l15) * LDT + kk * 32 + quad * 8];
                for (int dt = 0; dt < 4; ++dt) {
                    bf16x8 bV = *(const bf16x8*)
                        &Vt[(dt * 16 + l15) * LDT + kk * 32 + quad * 8];
                    o[ntq][dt] = __builtin_amdgcn_mfma_f32_16x16x32_bf16(
                        aP, bV, o[ntq][dt], 0, 0, 0);
                }
            }
        }
    }

    // epilogue: reduce l across quads (rows ntq*16+l15), broadcast, store
    for (int ntq = 0; ntq < 2; ++ntq) {
        float l = lsum[ntq];
        l += __shfl_xor(l, 16, 64);
        l += __shfl_xor(l, 32, 64);
        float linv = 1.0f / l;                 // row ntq*16 + l15
        float li[4];
        for (int r = 0; r < 4; ++r)
            li[r] = __shfl(linv, quad * 4 + r, 64);   // row ntq*16+quad*4+r
        for (int dt = 0; dt < 4; ++dt)
            for (int r = 0; r < 4; ++r)
                Op[(size_t)(ntq * 16 + quad * 4 + r) * D_MODEL + dt * 16 + l15] =
                    f2b(o[ntq][dt][r] * li[r]);
    }
}

// ---------------------------------------------------------------------------
extern "C" void kernel_launch(void* const* d_in, const int* in_sizes, int n_in,
                              void* d_out, int out_size, void* d_ws, size_t ws_size,
                              hipStream_t stream) {
    const float* x  = (const float*)d_in[0];
    const float* Wq = (const float*)d_in[1];
    const float* bq = (const float*)d_in[2];
    const float* Wk = (const float*)d_in[3];
    const float* bk = (const float*)d_in[4];
    const float* Wv = (const float*)d_in[5];
    const float* bv = (const float*)d_in[6];
    const float* Wo = (const float*)d_in[7];
    const float* bo = (const float*)d_in[8];
    float* out = (float*)d_out;

    u16* ws    = (u16*)d_ws;
    u16* xb    = ws;  ws += (size_t)M_ROWS * 1024;   // x bf16; reused as AO
    u16* WcatT = ws;  ws += (size_t)QKV_N * 1024;
    u16* WoT   = ws;  ws += 1024 * 1024;
    u16* QKV   = ws;  ws += (size_t)M_ROWS * QKV_N;
    u16* Vt_g  = ws;  ws += (size_t)KV_DIM * M_ROWS;
    u16* AO    = xb;                                  // alias: xb dead after gemm_qkv
    // total ws use: ~29 MB

    int nx = M_ROWS * 1024;
    cvt_f32_bf16<<<nx / (256 * 8), 256, 0, stream>>>(x, xb, nx);
    transpose_all<<<dim3(80, 32), 256, 0, stream>>>(Wq, Wk, Wv, Wo, WcatT, WoT);
    gemm_qkv<<<dim3(QKV_N / 128, M_ROWS / 64), 256, 0, stream>>>(
        xb, WcatT, bq, bk, bv, QKV, Vt_g);
    attn_kernel<<<512, 256, 0, stream>>>(QKV, Vt_g, AO);
    gemm_out<<<dim3(1024 / 128, M_ROWS / 64), 256, 0, stream>>>(AO, WoT, bo, out);
}

// Round 7
// 201.210 us; speedup vs baseline: 1.2696x; 1.0461x over previous
//
#include <hip/hip_runtime.h>
#include <hip/hip_bf16.h>
#include <stdint.h>

// Problem constants (GQA: D=1024, 16 heads, 4 groups, hd=64)
#define D_MODEL 1024
#define T_LEN   2048
#define BATCH   2
#define N_HEADS 16
#define KV_DIM  256
#define QKV_N   1536              // 1024 + 256 + 256 fused projection width
#define M_ROWS  (BATCH * T_LEN)   // 4096

typedef unsigned short u16;
typedef __bf16 bf16x8 __attribute__((ext_vector_type(8)));
typedef __bf16 bf16x2 __attribute__((ext_vector_type(2)));
typedef float  f32x4  __attribute__((ext_vector_type(4)));

__device__ __forceinline__ u16 f2b(float f) {
    uint32_t u = __builtin_bit_cast(uint32_t, f);
    u += 0x7FFFu + ((u >> 16) & 1u);   // round-to-nearest-even
    return (u16)(u >> 16);
}

// pack two f32 -> two bf16 in one u32 (lo = a, hi = b)
__device__ __forceinline__ uint32_t pk_bf16(float a, float b) {
#if __has_builtin(__builtin_amdgcn_cvt_pk_bf16_f32)
    bf16x2 v = __builtin_amdgcn_cvt_pk_bf16_f32(a, b);
    return __builtin_bit_cast(uint32_t, v);
#else
    return (uint32_t)f2b(a) | ((uint32_t)f2b(b) << 16);
#endif
}

// async global->LDS, 16B per lane; LDS dest = wave-uniform base + lane*16
__device__ __forceinline__ void gl_lds16(const void* g, void* l) {
    __builtin_amdgcn_global_load_lds(g, l, 16, 0, 0);
}

// ---------------------------------------------------------------------------
// prep: fp32->bf16 convert of x (blocks 0..2047) + all-weight transpose/cvt
// (blocks 2048..4607). One launch instead of two.
// ---------------------------------------------------------------------------
__global__ __launch_bounds__(256) void prep(
    const float* __restrict__ x,
    const float* __restrict__ Wq, const float* __restrict__ Wk,
    const float* __restrict__ Wv, const float* __restrict__ Wo,
    u16* __restrict__ xb, u16* __restrict__ WcatT, u16* __restrict__ WoT)
{
    __shared__ u16 tile[32][33];
    int id = blockIdx.x;
    int tid = threadIdx.x;
    if (id < 2048) {
        int i = (id * 256 + tid) * 8;
        float4 a = *(const float4*)&x[i];
        float4 c = *(const float4*)&x[i + 4];
        u16 r[8] = { f2b(a.x), f2b(a.y), f2b(a.z), f2b(a.w),
                     f2b(c.x), f2b(c.y), f2b(c.z), f2b(c.w) };
        *(uint4*)&xb[i] = *(const uint4*)r;
        return;
    }
    int t = id - 2048;
    int bx = t % 80;
    int k0 = (t / 80) * 32;
    const float* src; u16* dst; int N, n0;
    if (bx < 32)       { src = Wq; dst = WcatT;                   N = 1024; n0 = bx * 32; }
    else if (bx < 40)  { src = Wk; dst = WcatT + 1024 * 1024;     N = 256;  n0 = (bx - 32) * 32; }
    else if (bx < 48)  { src = Wv; dst = WcatT + 1280 * 1024;     N = 256;  n0 = (bx - 40) * 32; }
    else               { src = Wo; dst = WoT;                     N = 1024; n0 = (bx - 48) * 32; }
    for (int i = 0; i < 4; ++i) {
        int idx = tid + i * 256;
        int r = idx >> 5, c = idx & 31;
        tile[r][c] = f2b(src[(size_t)(k0 + r) * N + (n0 + c)]);
    }
    __syncthreads();
    for (int i = 0; i < 4; ++i) {
        int idx = tid + i * 256;
        int r = idx >> 5, c = idx & 31;   // r: n-local, c: k-local
        dst[(size_t)(n0 + r) * 1024 + (k0 + c)] = tile[c][r];
    }
}

// ---------------------------------------------------------------------------
// Fused QKV GEMM, 64x128 tile (M x N), 256 threads, wave w -> cols w*32..+31.
// Q written PRE-SCALED by 1/sqrt(64)*log2(e); K row-major; V transposed into
// Vt_glob[256 x M]. LDS unpadded, staged via global_load_lds 16B.
// ---------------------------------------------------------------------------
__global__ __launch_bounds__(256) void gemm_qkv(
    const u16* __restrict__ A, const u16* __restrict__ BT,
    const float* __restrict__ bq, const float* __restrict__ bk,
    const float* __restrict__ bv, u16* __restrict__ C,
    u16* __restrict__ Vt_glob)
{
    constexpr int K = 1024;
    constexpr float SCALE = 0.125f * 1.44269504088896f;
    __shared__ __align__(16) u16 As[64 * 64];
    __shared__ __align__(16) u16 Bs[128 * 64];

    int tid  = threadIdx.x;
    int lane = tid & 63, w = tid >> 6;
    int quad = lane >> 4, l15 = lane & 15;
    int m0 = blockIdx.y * 64, n0 = blockIdx.x * 128;
    int lr = lane >> 3, lc = (lane & 7) * 8;

    f32x4 acc[4][2] = {};

    for (int k0 = 0; k0 < K; k0 += 64) {
        for (int t = 0; t < 2; ++t) {
            int rb = t * 32 + w * 8;
            gl_lds16(&A[(size_t)(m0 + rb + lr) * K + k0 + lc], &As[rb * 64]);
        }
        for (int t = 0; t < 4; ++t) {
            int rb = t * 32 + w * 8;
            gl_lds16(&BT[(size_t)(n0 + rb + lr) * K + k0 + lc], &Bs[rb * 64]);
        }
        __syncthreads();
        for (int kk = 0; kk < 64; kk += 32) {
            bf16x8 a[4], b[2];
            for (int i = 0; i < 4; ++i)
                a[i] = *(const bf16x8*)&As[(i * 16 + l15) * 64 + kk + quad * 8];
            for (int j = 0; j < 2; ++j)
                b[j] = *(const bf16x8*)&Bs[(w * 32 + j * 16 + l15) * 64 + kk + quad * 8];
            for (int i = 0; i < 4; ++i)
                for (int j = 0; j < 2; ++j)
                    acc[i][j] = __builtin_amdgcn_mfma_f32_16x16x32_bf16(
                        a[i], b[j], acc[i][j], 0, 0, 0);
        }
        __syncthreads();
    }

    for (int j = 0; j < 2; ++j) {
        int col = n0 + w * 32 + j * 16 + l15;
        float bj = (col < 1024) ? bq[col] : (col < 1280) ? bk[col - 1024] : bv[col - 1280];
        for (int i = 0; i < 4; ++i) {
            int rowb = m0 + i * 16 + quad * 4;
            if (col < 1024) {
                for (int r = 0; r < 4; ++r)
                    C[(size_t)(rowb + r) * QKV_N + col] = f2b((acc[i][j][r] + bj) * SCALE);
            } else if (col < 1280) {
                for (int r = 0; r < 4; ++r)
                    C[(size_t)(rowb + r) * QKV_N + col] = f2b(acc[i][j][r] + bj);
            } else {
                u16 tmp[4];
                for (int r = 0; r < 4; ++r) tmp[r] = f2b(acc[i][j][r] + bj);
                *(uint64_t*)&Vt_glob[(size_t)(col - 1280) * M_ROWS + rowb] =
                    *(const uint64_t*)tmp;
            }
        }
    }
}

// ---------------------------------------------------------------------------
// Out-proj GEMM, 64x128 tile: out[M x 1024](fp32) = AO * WoT^T + bo.
// ---------------------------------------------------------------------------
__global__ __launch_bounds__(256) void gemm_out(
    const u16* __restrict__ A, const u16* __restrict__ BT,
    const float* __restrict__ bias, float* __restrict__ C)
{
    constexpr int K = 1024, N = 1024;
    __shared__ __align__(16) u16 As[64 * 64];
    __shared__ __align__(16) u16 Bs[128 * 64];

    int tid  = threadIdx.x;
    int lane = tid & 63, w = tid >> 6;
    int quad = lane >> 4, l15 = lane & 15;
    int m0 = blockIdx.y * 64, n0 = blockIdx.x * 128;
    int lr = lane >> 3, lc = (lane & 7) * 8;

    f32x4 acc[4][2] = {};

    for (int k0 = 0; k0 < K; k0 += 64) {
        for (int t = 0; t < 2; ++t) {
            int rb = t * 32 + w * 8;
            gl_lds16(&A[(size_t)(m0 + rb + lr) * K + k0 + lc], &As[rb * 64]);
        }
        for (int t = 0; t < 4; ++t) {
            int rb = t * 32 + w * 8;
            gl_lds16(&BT[(size_t)(n0 + rb + lr) * K + k0 + lc], &Bs[rb * 64]);
        }
        __syncthreads();
        for (int kk = 0; kk < 64; kk += 32) {
            bf16x8 a[4], b[2];
            for (int i = 0; i < 4; ++i)
                a[i] = *(const bf16x8*)&As[(i * 16 + l15) * 64 + kk + quad * 8];
            for (int j = 0; j < 2; ++j)
                b[j] = *(const bf16x8*)&Bs[(w * 32 + j * 16 + l15) * 64 + kk + quad * 8];
            for (int i = 0; i < 4; ++i)
                for (int j = 0; j < 2; ++j)
                    acc[i][j] = __builtin_amdgcn_mfma_f32_16x16x32_bf16(
                        a[i], b[j], acc[i][j], 0, 0, 0);
        }
        __syncthreads();
    }

    for (int j = 0; j < 2; ++j) {
        int col = n0 + w * 32 + j * 16 + l15;
        float bj = bias[col];
        for (int i = 0; i < 4; ++i) {
            int rowb = m0 + i * 16 + quad * 4;
            for (int r = 0; r < 4; ++r)
                C[(size_t)(rowb + r) * N + col] = acc[i][j][r] + bj;
        }
    }
}

// ---------------------------------------------------------------------------
// Flash attention v3 (causal, GQA-shared, split-K-in-block).
// Block = (b, group, 32-row q-strip), 512 threads = 8 waves = 4 heads x 2
// K-halves. Fixed-max softmax partials are associative: each K-half wave
// accumulates (O, l) independently; epilogue combines via LDS.
// kh0 runs tiles [0,n0), kh1 [n0,i); both loop n0=ceil(i/2) times (kh1's
// extra iter inactive) so barriers match. Co-resident pair (gid,gid+256)
// sums to exactly 17 slots. Same-(g,b) blocks share gid%8 -> same XCD.
// LDS 57.3KB: K/V stride 72; P 32-wide stride 40, PV per 32-key half.
// ---------------------------------------------------------------------------
__global__ __launch_bounds__(512, 4) void attn_kernel(
    const u16* __restrict__ QKV,     // [B*T, 1536] bf16 (Qscaled | K | -)
    const u16* __restrict__ Vt_glob, // [256, B*T]  bf16 (V transposed)
    u16* __restrict__ AO)            // [B*T, 1024] bf16
{
    constexpr int LDT = 72;   // K/V row stride (u16)
    constexpr int LDP = 40;   // P row stride (u16): 32 cols + pad, 80B
    __shared__ __align__(16) u16 KVs[2][2][64 * LDT];  // [kh][K=0,V=1]
    __shared__ __align__(16) u16 Ps[8][32 * LDP];

    int tid  = threadIdx.x;
    int lane = tid & 63, w = tid >> 6;       // w 0..7
    int hl = w & 3, kh = w >> 2;
    int quad = lane >> 4, l15 = lane & 15;

    int gid  = blockIdx.x;
    int half = gid >> 8, rid = gid & 255;
    int j = half ? 63 - (rid >> 3) : (rid >> 3);   // q-strip (32 rows)
    int g = (rid >> 1) & 3;
    int b = rid & 1;
    int head = g * 4 + hl;
    int q0 = j * 32;
    int iters = (j >> 1) + 1;                      // total k-tiles (64 keys)
    int n0 = (iters + 1) >> 1;                     // kh0: tiles [0, n0)
    int n1 = iters - n0;                           // kh1: tiles [n0, iters)
    int myn    = kh ? n1 : n0;
    int base_t = kh ? n0 : 0;

    const u16* Qp = QKV + ((size_t)b * T_LEN + q0) * QKV_N + head * 64;
    const u16* Kp = QKV + (size_t)b * T_LEN * QKV_N + 1024 + g * 64;
    const u16* Vp = Vt_glob + (size_t)g * 64 * M_ROWS + b * T_LEN;
    u16*       Op = AO + ((size_t)b * T_LEN + q0) * D_MODEL + head * 64;

    u16* Ks = KVs[kh][0];
    u16* Vt = KVs[kh][1];
    u16* Pw = Ps[w];

    // Q fragments (loop-invariant): B-frag Q[n=qrow][k]
    bf16x8 Qfrag[2][2];
    #pragma unroll
    for (int ntq = 0; ntq < 2; ++ntq)
        #pragma unroll
        for (int kk = 0; kk < 2; ++kk)
            Qfrag[ntq][kk] = *(const bf16x8*)
                &Qp[(size_t)(ntq * 16 + l15) * QKV_N + kk * 32 + quad * 8];

    f32x4 o[2][4] = {};
    float lsum[2] = {0.f, 0.f};

    // staging coords within this K-half's 4-wave group (tids kh*256..+255)
    int tid0 = tid & 255;
    int r0 = tid0 >> 3, c0 = (tid0 & 7) << 3;      // rows r0, r0+32

    // prefetch first tile (clamped: kh1 may have zero work)
    int tg0 = min(base_t, iters - 1);
    uint4 Kreg[2], Vreg[2];
    Kreg[0] = *(const uint4*)&Kp[(size_t)(tg0 * 64 + r0) * QKV_N + c0];
    Kreg[1] = *(const uint4*)&Kp[(size_t)(tg0 * 64 + r0 + 32) * QKV_N + c0];
    Vreg[0] = *(const uint4*)&Vp[(size_t)r0 * M_ROWS + tg0 * 64 + c0];
    Vreg[1] = *(const uint4*)&Vp[(size_t)(r0 + 32) * M_ROWS + tg0 * 64 + c0];

    for (int kt = 0; kt < n0; ++kt) {
        int tg = base_t + kt;
        bool active = kt < myn;
        bool diag = active && (tg == iters - 1);
        __syncthreads();   // prior-iter reads of Ks/Vt complete
        *(uint4*)&Ks[r0 * LDT + c0]        = Kreg[0];
        *(uint4*)&Ks[(r0 + 32) * LDT + c0] = Kreg[1];
        *(uint4*)&Vt[r0 * LDT + c0]        = Vreg[0];
        *(uint4*)&Vt[(r0 + 32) * LDT + c0] = Vreg[1];
        __syncthreads();
        if (kt + 1 < n0) {
            int tgn = min(base_t + kt + 1, iters - 1);
            Kreg[0] = *(const uint4*)&Kp[(size_t)(tgn * 64 + r0) * QKV_N + c0];
            Kreg[1] = *(const uint4*)&Kp[(size_t)(tgn * 64 + r0 + 32) * QKV_N + c0];
            Vreg[0] = *(const uint4*)&Vp[(size_t)r0 * M_ROWS + tgn * 64 + c0];
            Vreg[1] = *(const uint4*)&Vp[(size_t)(r0 + 32) * M_ROWS + tgn * 64 + c0];
        }
        if (!active) continue;

        // S^T = K * Q^T, both q-subtiles share each aK read.
        // D: row(quad*4+reg)=key, col(l15)=qrow.
        f32x4 s[2][4] = {};
        #pragma unroll
        for (int kk = 0; kk < 2; ++kk) {
            bf16x8 bQ0 = Qfrag[0][kk], bQ1 = Qfrag[1][kk];
            #pragma unroll
            for (int ntk = 0; ntk < 4; ++ntk) {
                bf16x8 aK = *(const bf16x8*)
                    &Ks[(ntk * 16 + l15) * LDT + kk * 32 + quad * 8];
                s[0][ntk] = __builtin_amdgcn_mfma_f32_16x16x32_bf16(
                    aK, bQ0, s[0][ntk], 0, 0, 0);
                s[1][ntk] = __builtin_amdgcn_mfma_f32_16x16x32_bf16(
                    aK, bQ1, s[1][ntk], 0, 0, 0);
            }
        }

        // exp2 (Q pre-scaled to log2 domain) + causal mask (diag tile only)
        uint2 pr[2][4];
        #pragma unroll
        for (int ntq = 0; ntq < 2; ++ntq) {
            int qrow = q0 + ntq * 16 + l15;
            float lacc = 0.f;
            #pragma unroll
            for (int ntk = 0; ntk < 4; ++ntk) {
                float p0, p1, p2, p3;
                if (diag) {
                    int key = tg * 64 + ntk * 16 + quad * 4;
                    p0 = (key + 0 <= qrow) ? exp2f(s[ntq][ntk][0]) : 0.f;
                    p1 = (key + 1 <= qrow) ? exp2f(s[ntq][ntk][1]) : 0.f;
                    p2 = (key + 2 <= qrow) ? exp2f(s[ntq][ntk][2]) : 0.f;
                    p3 = (key + 3 <= qrow) ? exp2f(s[ntq][ntk][3]) : 0.f;
                } else {
                    p0 = exp2f(s[ntq][ntk][0]);
                    p1 = exp2f(s[ntq][ntk][1]);
                    p2 = exp2f(s[ntq][ntk][2]);
                    p3 = exp2f(s[ntq][ntk][3]);
                }
                lacc += (p0 + p1) + (p2 + p3);
                pr[ntq][ntk].x = pk_bf16(p0, p1);
                pr[ntq][ntk].y = pk_bf16(p2, p3);
            }
            lsum[ntq] += lacc;
        }

        // PV per 32-key half: write P (2 tiles), read back A-frags, hoisted bV
        #pragma unroll
        for (int kkp = 0; kkp < 2; ++kkp) {
            #pragma unroll
            for (int ntq = 0; ntq < 2; ++ntq) {
                *(uint2*)&Pw[(ntq * 16 + l15) * LDP + quad * 4] =
                    pr[ntq][2 * kkp];
                *(uint2*)&Pw[(ntq * 16 + l15) * LDP + 16 + quad * 4] =
                    pr[ntq][2 * kkp + 1];
            }
            bf16x8 bV[4];
            #pragma unroll
            for (int dt = 0; dt < 4; ++dt)
                bV[dt] = *(const bf16x8*)
                    &Vt[(dt * 16 + l15) * LDT + kkp * 32 + quad * 8];
            #pragma unroll
            for (int ntq = 0; ntq < 2; ++ntq) {
                bf16x8 aP = *(const bf16x8*)
                    &Pw[(ntq * 16 + l15) * LDP + quad * 8];
                #pragma unroll
                for (int dt = 0; dt < 4; ++dt)
                    o[ntq][dt] = __builtin_amdgcn_mfma_f32_16x16x32_bf16(
                        aP, bV[dt], o[ntq][dt], 0, 0, 0);
            }
        }
    }

    // combine the two K-halves per head via LDS (overlays dead K/V buffers)
    __syncthreads();
    float* xch = (float*)&KVs[0][0][0];   // [4 heads][34][64 lanes] f32
    if (kh == 1) {
        #pragma unroll
        for (int ntq = 0; ntq < 2; ++ntq)
            #pragma unroll
            for (int dt = 0; dt < 4; ++dt)
                #pragma unroll
                for (int r = 0; r < 4; ++r)
                    xch[(hl * 34 + ntq * 16 + dt * 4 + r) * 64 + lane] =
                        o[ntq][dt][r];
        xch[(hl * 34 + 32) * 64 + lane] = lsum[0];
        xch[(hl * 34 + 33) * 64 + lane] = lsum[1];
    }
    __syncthreads();
    if (kh == 0) {
        #pragma unroll
        for (int ntq = 0; ntq < 2; ++ntq)
            #pragma unroll
            for (int dt = 0; dt < 4; ++dt)
                #pragma unroll
                for (int r = 0; r < 4; ++r)
                    o[ntq][dt][r] +=
                        xch[(hl * 34 + ntq * 16 + dt * 4 + r) * 64 + lane];
        lsum[0] += xch[(hl * 34 + 32) * 64 + lane];
        lsum[1] += xch[(hl * 34 + 33) * 64 + lane];

        #pragma unroll
        for (int ntq = 0; ntq < 2; ++ntq) {
            float l = lsum[ntq];
            l += __shfl_xor(l, 16, 64);
            l += __shfl_xor(l, 32, 64);
            float linv = 1.0f / l;                 // row ntq*16 + l15
            float li[4];
            #pragma unroll
            for (int r = 0; r < 4; ++r)
                li[r] = __shfl(linv, quad * 4 + r, 64);
            #pragma unroll
            for (int dt = 0; dt < 4; ++dt)
                #pragma unroll
                for (int r = 0; r < 4; ++r)
                    Op[(size_t)(ntq * 16 + quad * 4 + r) * D_MODEL
                       + dt * 16 + l15] = f2b(o[ntq][dt][r] * li[r]);
        }
    }
}

// ---------------------------------------------------------------------------
extern "C" void kernel_launch(void* const* d_in, const int* in_sizes, int n_in,
                              void* d_out, int out_size, void* d_ws, size_t ws_size,
                              hipStream_t stream) {
    const float* x  = (const float*)d_in[0];
    const float* Wq = (const float*)d_in[1];
    const float* bq = (const float*)d_in[2];
    const float* Wk = (const float*)d_in[3];
    const float* bk = (const float*)d_in[4];
    const float* Wv = (const float*)d_in[5];
    const float* bv = (const float*)d_in[6];
    const float* Wo = (const float*)d_in[7];
    const float* bo = (const float*)d_in[8];
    float* out = (float*)d_out;

    u16* ws    = (u16*)d_ws;
    u16* xb    = ws;  ws += (size_t)M_ROWS * 1024;   // x bf16; reused as AO
    u16* WcatT = ws;  ws += (size_t)QKV_N * 1024;
    u16* WoT   = ws;  ws += 1024 * 1024;
    u16* QKV   = ws;  ws += (size_t)M_ROWS * QKV_N;
    u16* Vt_g  = ws;  ws += (size_t)KV_DIM * M_ROWS;
    u16* AO    = xb;                                  // alias: xb dead after gemm_qkv
    // total ws use: ~29 MB

    prep<<<2048 + 2560, 256, 0, stream>>>(x, Wq, Wk, Wv, Wo, xb, WcatT, WoT);
    gemm_qkv<<<dim3(QKV_N / 128, M_ROWS / 64), 256, 0, stream>>>(
        xb, WcatT, bq, bk, bv, QKV, Vt_g);
    attn_kernel<<<512, 512, 0, stream>>>(QKV, Vt_g, AO);
    gemm_out<<<dim3(1024 / 128, M_ROWS / 64), 256, 0, stream>>>(AO, WoT, bo, out);
}

// Round 8
// 191.844 us; speedup vs baseline: 1.3316x; 1.0488x over previous
//
#include <hip/hip_runtime.h>
#include <hip/hip_bf16.h>
#include <stdint.h>

// Problem constants (GQA: D=1024, 16 heads, 4 groups, hd=64)
#define D_MODEL 1024
#define T_LEN   2048
#define BATCH   2
#define N_HEADS 16
#define KV_DIM  256
#define QKV_N   1536              // 1024 + 256 + 256 fused projection width
#define M_ROWS  (BATCH * T_LEN)   // 4096

typedef unsigned short u16;
typedef __bf16 bf16x8 __attribute__((ext_vector_type(8)));
typedef __bf16 bf16x2 __attribute__((ext_vector_type(2)));
typedef float  f32x4  __attribute__((ext_vector_type(4)));

__device__ __forceinline__ u16 f2b(float f) {
    uint32_t u = __builtin_bit_cast(uint32_t, f);
    u += 0x7FFFu + ((u >> 16) & 1u);   // round-to-nearest-even
    return (u16)(u >> 16);
}

// pack two f32 -> two bf16 in one u32 (lo = a, hi = b)
__device__ __forceinline__ uint32_t pk_bf16(float a, float b) {
#if __has_builtin(__builtin_amdgcn_cvt_pk_bf16_f32)
    bf16x2 v = __builtin_amdgcn_cvt_pk_bf16_f32(a, b);
    return __builtin_bit_cast(uint32_t, v);
#else
    return (uint32_t)f2b(a) | ((uint32_t)f2b(b) << 16);
#endif
}

// async global->LDS, 16B per lane; LDS dest = wave-uniform base + lane*16
__device__ __forceinline__ void gl_lds16(const void* g, void* l) {
    __builtin_amdgcn_global_load_lds(g, l, 16, 0, 0);
}

// ---------------------------------------------------------------------------
// prep: fp32->bf16 convert of x (blocks 0..2047) + all-weight transpose/cvt
// (blocks 2048..4607). One launch.
// ---------------------------------------------------------------------------
__global__ __launch_bounds__(256) void prep(
    const float* __restrict__ x,
    const float* __restrict__ Wq, const float* __restrict__ Wk,
    const float* __restrict__ Wv, const float* __restrict__ Wo,
    u16* __restrict__ xb, u16* __restrict__ WcatT, u16* __restrict__ WoT)
{
    __shared__ u16 tile[32][33];
    int id = blockIdx.x;
    int tid = threadIdx.x;
    if (id < 2048) {
        int i = (id * 256 + tid) * 8;
        float4 a = *(const float4*)&x[i];
        float4 c = *(const float4*)&x[i + 4];
        u16 r[8] = { f2b(a.x), f2b(a.y), f2b(a.z), f2b(a.w),
                     f2b(c.x), f2b(c.y), f2b(c.z), f2b(c.w) };
        *(uint4*)&xb[i] = *(const uint4*)r;
        return;
    }
    int t = id - 2048;
    int bx = t % 80;
    int k0 = (t / 80) * 32;
    const float* src; u16* dst; int N, n0;
    if (bx < 32)       { src = Wq; dst = WcatT;                   N = 1024; n0 = bx * 32; }
    else if (bx < 40)  { src = Wk; dst = WcatT + 1024 * 1024;     N = 256;  n0 = (bx - 32) * 32; }
    else if (bx < 48)  { src = Wv; dst = WcatT + 1280 * 1024;     N = 256;  n0 = (bx - 40) * 32; }
    else               { src = Wo; dst = WoT;                     N = 1024; n0 = (bx - 48) * 32; }
    for (int i = 0; i < 4; ++i) {
        int idx = tid + i * 256;
        int r = idx >> 5, c = idx & 31;
        tile[r][c] = f2b(src[(size_t)(k0 + r) * N + (n0 + c)]);
    }
    __syncthreads();
    for (int i = 0; i < 4; ++i) {
        int idx = tid + i * 256;
        int r = idx >> 5, c = idx & 31;   // r: n-local, c: k-local
        dst[(size_t)(n0 + r) * 1024 + (k0 + c)] = tile[c][r];
    }
}

// ---------------------------------------------------------------------------
// Fused QKV GEMM, 64x128 tile. Q -> Qb[4096x1024] PRE-SCALED (log2 domain).
// K -> Kpack, V -> Vpack: FRAGMENT-MAJOR layouts so attention waves load
// MFMA fragments directly from global (lane's 16B at base+lane*16):
//   Kpack[(b,g)][t64][kk][ntk][lane=quad*16+l15][8e]
//       = K[key = t64*64+ntk*16+l15][d = kk*32+quad*8+e]
//   Vpack[(b,g)][t64][kkp][dt][lane=quad*16+l15][8e]
//       = V[key = t64*64+kkp*32+quad*8+e][d = dt*16+l15]
// ---------------------------------------------------------------------------
__global__ __launch_bounds__(256) void gemm_qkv(
    const u16* __restrict__ A, const u16* __restrict__ BT,
    const float* __restrict__ bq, const float* __restrict__ bk,
    const float* __restrict__ bv, u16* __restrict__ Qb,
    u16* __restrict__ Kpack, u16* __restrict__ Vpack)
{
    constexpr int K = 1024;
    constexpr float SCALE = 0.125f * 1.44269504088896f;
    __shared__ __align__(16) u16 As[64 * 64];
    __shared__ __align__(16) u16 Bs[128 * 64];

    int tid  = threadIdx.x;
    int lane = tid & 63, w = tid >> 6;
    int quad = lane >> 4, l15 = lane & 15;
    int m0 = blockIdx.y * 64, n0 = blockIdx.x * 128;
    int lr = lane >> 3, lc = (lane & 7) * 8;

    f32x4 acc[4][2] = {};

    for (int k0 = 0; k0 < K; k0 += 64) {
        for (int t = 0; t < 2; ++t) {
            int rb = t * 32 + w * 8;
            gl_lds16(&A[(size_t)(m0 + rb + lr) * K + k0 + lc], &As[rb * 64]);
        }
        for (int t = 0; t < 4; ++t) {
            int rb = t * 32 + w * 8;
            gl_lds16(&BT[(size_t)(n0 + rb + lr) * K + k0 + lc], &Bs[rb * 64]);
        }
        __syncthreads();
        for (int kk = 0; kk < 64; kk += 32) {
            bf16x8 a[4], b[2];
            for (int i = 0; i < 4; ++i)
                a[i] = *(const bf16x8*)&As[(i * 16 + l15) * 64 + kk + quad * 8];
            for (int j = 0; j < 2; ++j)
                b[j] = *(const bf16x8*)&Bs[(w * 32 + j * 16 + l15) * 64 + kk + quad * 8];
            for (int i = 0; i < 4; ++i)
                for (int j = 0; j < 2; ++j)
                    acc[i][j] = __builtin_amdgcn_mfma_f32_16x16x32_bf16(
                        a[i], b[j], acc[i][j], 0, 0, 0);
        }
        __syncthreads();
    }

    for (int j = 0; j < 2; ++j) {
        int col = n0 + w * 32 + j * 16 + l15;
        float bj = (col < 1024) ? bq[col] : (col < 1280) ? bk[col - 1024] : bv[col - 1280];
        for (int i = 0; i < 4; ++i) {
            int rowb = m0 + i * 16 + quad * 4;       // 4 consecutive rows
            int bb = rowb >> 11, keyloc = rowb & 2047;
            int t64 = keyloc >> 6;
            if (col < 1024) {
                for (int r = 0; r < 4; ++r)
                    Qb[(size_t)(rowb + r) * 1024 + col] =
                        f2b((acc[i][j][r] + bj) * SCALE);
            } else if (col < 1280) {
                int d = col - 1024; int g = d >> 6; d &= 63;
                int kk = d >> 5, qd = (d >> 3) & 3, e = d & 7;
                int ntk = (keyloc >> 4) & 3, l15k = keyloc & 15;
                size_t base = ((((size_t)(bb * 4 + g) * 32 + t64) * 2 + kk) * 4
                               + ntk) * 512 + qd * 128 + l15k * 8 + e;
                for (int r = 0; r < 4; ++r)
                    Kpack[base + r * 8] = f2b(acc[i][j][r] + bj);
            } else {
                int d = col - 1280; int g = d >> 6; d &= 63;
                int dt = d >> 4, l15v = d & 15;
                int kkp = (keyloc >> 5) & 1, qv = (keyloc >> 3) & 3, e0 = keyloc & 7;
                u16 tmp[4];
                for (int r = 0; r < 4; ++r) tmp[r] = f2b(acc[i][j][r] + bj);
                size_t base = ((((size_t)(bb * 4 + g) * 32 + t64) * 2 + kkp) * 4
                               + dt) * 512 + (qv * 16 + l15v) * 8 + e0;
                *(uint64_t*)&Vpack[base] = *(const uint64_t*)tmp;
            }
        }
    }
}

// ---------------------------------------------------------------------------
// Out-proj GEMM, 64x128 tile: out[M x 1024](fp32) = AO * WoT^T + bo.
// ---------------------------------------------------------------------------
__global__ __launch_bounds__(256) void gemm_out(
    const u16* __restrict__ A, const u16* __restrict__ BT,
    const float* __restrict__ bias, float* __restrict__ C)
{
    constexpr int K = 1024, N = 1024;
    __shared__ __align__(16) u16 As[64 * 64];
    __shared__ __align__(16) u16 Bs[128 * 64];

    int tid  = threadIdx.x;
    int lane = tid & 63, w = tid >> 6;
    int quad = lane >> 4, l15 = lane & 15;
    int m0 = blockIdx.y * 64, n0 = blockIdx.x * 128;
    int lr = lane >> 3, lc = (lane & 7) * 8;

    f32x4 acc[4][2] = {};

    for (int k0 = 0; k0 < K; k0 += 64) {
        for (int t = 0; t < 2; ++t) {
            int rb = t * 32 + w * 8;
            gl_lds16(&A[(size_t)(m0 + rb + lr) * K + k0 + lc], &As[rb * 64]);
        }
        for (int t = 0; t < 4; ++t) {
            int rb = t * 32 + w * 8;
            gl_lds16(&BT[(size_t)(n0 + rb + lr) * K + k0 + lc], &Bs[rb * 64]);
        }
        __syncthreads();
        for (int kk = 0; kk < 64; kk += 32) {
            bf16x8 a[4], b[2];
            for (int i = 0; i < 4; ++i)
                a[i] = *(const bf16x8*)&As[(i * 16 + l15) * 64 + kk + quad * 8];
            for (int j = 0; j < 2; ++j)
                b[j] = *(const bf16x8*)&Bs[(w * 32 + j * 16 + l15) * 64 + kk + quad * 8];
            for (int i = 0; i < 4; ++i)
                for (int j = 0; j < 2; ++j)
                    acc[i][j] = __builtin_amdgcn_mfma_f32_16x16x32_bf16(
                        a[i], b[j], acc[i][j], 0, 0, 0);
        }
        __syncthreads();
    }

    for (int j = 0; j < 2; ++j) {
        int col = n0 + w * 32 + j * 16 + l15;
        float bj = bias[col];
        for (int i = 0; i < 4; ++i) {
            int rowb = m0 + i * 16 + quad * 4;
            for (int r = 0; r < 4; ++r)
                C[(size_t)(rowb + r) * N + col] = acc[i][j][r] + bj;
        }
    }
}

// ---------------------------------------------------------------------------
// Flash attention v4 (causal, GQA): BARRIER-FREE. Block = (b,g,strip of 32
// q-rows), 4 independent waves = the group's 4 heads. K/V fragments loaded
// DIRECTLY from global fragment-packed layouts (coalesced lane*16B) -- no
// LDS staging, no __syncthreads. P round-trips through wave-private LDS
// (DS ops in-order per wave). Fixed-max softmax in log2 domain (Q
// pre-scaled), mask only on diagonal tile, l reduced once in epilogue.
// Grid 512 longest-strip-first (j = 63 - gid>>3) for backfill balance;
// gid&7 = (b,g) -> same-XCD K/V L2 locality.
// ---------------------------------------------------------------------------
__global__ __launch_bounds__(256, 4) void attn_kernel(
    const u16* __restrict__ Qb,     // [B*T, 1024] bf16, pre-scaled
    const u16* __restrict__ Kpack,  // fragment-packed K
    const u16* __restrict__ Vpack,  // fragment-packed V
    u16* __restrict__ AO)           // [B*T, 1024] bf16
{
    constexpr int LDP = 72;   // P row stride (u16)
    __shared__ __align__(16) u16 Ps[4][32 * LDP];   // wave-private P tiles

    int tid  = threadIdx.x;
    int lane = tid & 63, w = tid >> 6;
    int quad = lane >> 4, l15 = lane & 15;

    int gid = blockIdx.x;
    int b = gid & 1, g = (gid >> 1) & 3;
    int j = 63 - (gid >> 3);                 // longest strips dispatch first
    int head = g * 4 + w;
    int q0 = j * 32;
    int iters = (j >> 1) + 1;                // k-tiles of 64 keys

    const u16* Qp = Qb + ((size_t)b * T_LEN + q0) * 1024 + head * 64;
    const u16* Kp = Kpack + (size_t)(b * 4 + g) * 131072 + (size_t)lane * 8;
    const u16* Vp = Vpack + (size_t)(b * 4 + g) * 131072 + (size_t)lane * 8;
    u16*       Op = AO + ((size_t)b * T_LEN + q0) * D_MODEL + head * 64;
    u16* Pw = Ps[w];

    // Q fragments (loop-invariant): B-frag Q[n=qrow][k=d]
    bf16x8 Qfrag[2][2];
    #pragma unroll
    for (int ntq = 0; ntq < 2; ++ntq)
        #pragma unroll
        for (int kk = 0; kk < 2; ++kk)
            Qfrag[ntq][kk] = *(const bf16x8*)
                &Qp[(size_t)(ntq * 16 + l15) * 1024 + kk * 32 + quad * 8];

    f32x4 o[2][4] = {};
    float lsum[2] = {0.f, 0.f};

    for (int tg = 0; tg < iters; ++tg) {
        bool diag = (tg == iters - 1);

        // K fragments straight from global (coalesced 1KB per load)
        const u16* kb = Kp + (size_t)tg * 4096;
        bf16x8 aK[2][4];
        #pragma unroll
        for (int kk = 0; kk < 2; ++kk)
            #pragma unroll
            for (int ntk = 0; ntk < 4; ++ntk)
                aK[kk][ntk] = *(const bf16x8*)(kb + (kk * 4 + ntk) * 512);

        // S^T = K * Q^T per q-subtile; exp2; packed P -> wave-private LDS
        #pragma unroll
        for (int ntq = 0; ntq < 2; ++ntq) {
            f32x4 s[4] = {};
            #pragma unroll
            for (int kk = 0; kk < 2; ++kk) {
                bf16x8 bQ = Qfrag[ntq][kk];
                #pragma unroll
                for (int ntk = 0; ntk < 4; ++ntk)
                    s[ntk] = __builtin_amdgcn_mfma_f32_16x16x32_bf16(
                        aK[kk][ntk], bQ, s[ntk], 0, 0, 0);
            }
            int qrow = q0 + ntq * 16 + l15;
            float lacc = 0.f;
            #pragma unroll
            for (int ntk = 0; ntk < 4; ++ntk) {
                float p0, p1, p2, p3;
                if (diag) {
                    int key = tg * 64 + ntk * 16 + quad * 4;
                    p0 = (key + 0 <= qrow) ? exp2f(s[ntk][0]) : 0.f;
                    p1 = (key + 1 <= qrow) ? exp2f(s[ntk][1]) : 0.f;
                    p2 = (key + 2 <= qrow) ? exp2f(s[ntk][2]) : 0.f;
                    p3 = (key + 3 <= qrow) ? exp2f(s[ntk][3]) : 0.f;
                } else {
                    p0 = exp2f(s[ntk][0]);
                    p1 = exp2f(s[ntk][1]);
                    p2 = exp2f(s[ntk][2]);
                    p3 = exp2f(s[ntk][3]);
                }
                lacc += (p0 + p1) + (p2 + p3);
                uint2 pv;
                pv.x = pk_bf16(p0, p1);
                pv.y = pk_bf16(p2, p3);
                *(uint2*)&Pw[(ntq * 16 + l15) * LDP + ntk * 16 + quad * 4] = pv;
            }
            lsum[ntq] += lacc;
        }

        // O += P V : V fragments straight from global; aP from wave-private P
        const u16* vb = Vp + (size_t)tg * 4096;
        #pragma unroll
        for (int kkp = 0; kkp < 2; ++kkp) {
            bf16x8 bV[4];
            #pragma unroll
            for (int dt = 0; dt < 4; ++dt)
                bV[dt] = *(const bf16x8*)(vb + (kkp * 4 + dt) * 512);
            #pragma unroll
            for (int ntq = 0; ntq < 2; ++ntq) {
                bf16x8 aP = *(const bf16x8*)
                    &Pw[(ntq * 16 + l15) * LDP + kkp * 32 + quad * 8];
                #pragma unroll
                for (int dt = 0; dt < 4; ++dt)
                    o[ntq][dt] = __builtin_amdgcn_mfma_f32_16x16x32_bf16(
                        aP, bV[dt], o[ntq][dt], 0, 0, 0);
            }
        }
    }

    // epilogue: reduce l across quads (once), normalize, store
    #pragma unroll
    for (int ntq = 0; ntq < 2; ++ntq) {
        float l = lsum[ntq];
        l += __shfl_xor(l, 16, 64);
        l += __shfl_xor(l, 32, 64);
        float linv = 1.0f / l;                 // row ntq*16 + l15
        float li[4];
        #pragma unroll
        for (int r = 0; r < 4; ++r)
            li[r] = __shfl(linv, quad * 4 + r, 64);
        #pragma unroll
        for (int dt = 0; dt < 4; ++dt)
            #pragma unroll
            for (int r = 0; r < 4; ++r)
                Op[(size_t)(ntq * 16 + quad * 4 + r) * D_MODEL + dt * 16 + l15] =
                    f2b(o[ntq][dt][r] * li[r]);
    }
}

// ---------------------------------------------------------------------------
extern "C" void kernel_launch(void* const* d_in, const int* in_sizes, int n_in,
                              void* d_out, int out_size, void* d_ws, size_t ws_size,
                              hipStream_t stream) {
    const float* x  = (const float*)d_in[0];
    const float* Wq = (const float*)d_in[1];
    const float* bq = (const float*)d_in[2];
    const float* Wk = (const float*)d_in[3];
    const float* bk = (const float*)d_in[4];
    const float* Wv = (const float*)d_in[5];
    const float* bv = (const float*)d_in[6];
    const float* Wo = (const float*)d_in[7];
    const float* bo = (const float*)d_in[8];
    float* out = (float*)d_out;

    u16* ws    = (u16*)d_ws;
    u16* xb    = ws;  ws += (size_t)M_ROWS * 1024;   // x bf16; reused as AO
    u16* WcatT = ws;  ws += (size_t)QKV_N * 1024;
    u16* WoT   = ws;  ws += 1024 * 1024;
    u16* Qb    = ws;  ws += (size_t)M_ROWS * 1024;
    u16* Kpack = ws;  ws += (size_t)M_ROWS * KV_DIM;
    u16* Vpack = ws;  ws += (size_t)M_ROWS * KV_DIM;
    u16* AO    = xb;                                  // alias: xb dead after gemm_qkv
    // total ws use: ~25 MB

    prep<<<2048 + 2560, 256, 0, stream>>>(x, Wq, Wk, Wv, Wo, xb, WcatT, WoT);
    gemm_qkv<<<dim3(QKV_N / 128, M_ROWS / 64), 256, 0, stream>>>(
        xb, WcatT, bq, bk, bv, Qb, Kpack, Vpack);
    attn_kernel<<<512, 256, 0, stream>>>(Qb, Kpack, Vpack, AO);
    gemm_out<<<dim3(1024 / 128, M_ROWS / 64), 256, 0, stream>>>(AO, WoT, bo, out);
}